// Round 5
// baseline (801.225 us; speedup 1.0000x reference)
//
#include <hip/hip_runtime.h>
#include <cstdint>
#include <cstddef>

typedef __bf16 bf16x8 __attribute__((ext_vector_type(8)));
typedef float  f32x4  __attribute__((ext_vector_type(4)));

#define MFMA16(a,b,c) __builtin_amdgcn_mfma_f32_16x16x32_bf16((a),(b),(c),0,0,0)

// ---------- helpers ----------
__device__ __forceinline__ uint f2bf1(float f){
  uint u = __builtin_bit_cast(uint, f);
  u += 0x7FFFu + ((u >> 16) & 1u);   // RNE to bf16
  return u >> 16;
}
__device__ __forceinline__ uint pack2(float a, float b){  // RNE (cold paths)
  return f2bf1(a) | (f2bf1(b) << 16);
}
// fast pack: round-half-away via biased add + v_perm_b32 (3 VALU ops)
__device__ __forceinline__ uint pack2f(float a, float b){
  uint ua = __builtin_bit_cast(uint, a) + 0x8000u;
  uint ub = __builtin_bit_cast(uint, b) + 0x8000u;
  return __builtin_amdgcn_perm(ub, ua, 0x07060302u); // {ua.b2,ua.b3,ub.b2,ub.b3}
}
__device__ __forceinline__ float bflo(uint d){ return __builtin_bit_cast(float, d << 16); }
__device__ __forceinline__ float bfhi(uint d){ return __builtin_bit_cast(float, d & 0xFFFF0000u); }

// =====================================================================
// Kernel 1: transpose triplane (B,3,C,H,W) fp32 -> (B,3,H,W,C) bf16
// =====================================================================
__global__ __launch_bounds__(256, 4) void transpose_k(
    const float* __restrict__ tri, ushort* __restrict__ tp)
{
  __shared__ ushort st[64 * 41];
  const int bi  = blockIdx.x;
  const int xb  = bi & 3;
  const int y   = (bi >> 2) & 255;
  const int q   = bi >> 10;            // b*3+pl, 0..11
  const int tid = threadIdx.x;
  const float* src = tri + (size_t)q * 40 * 65536 + y * 256 + xb * 64;
#pragma unroll
  for (int it = 0; it < 10; it++){
    int lin = it * 256 + tid;          // 0..2559
    int c = lin >> 6, x = lin & 63;
    float v = src[(size_t)c * 65536 + x];
    st[x * 41 + c] = (ushort)f2bf1(v);
  }
  __syncthreads();
  uint* dst = (uint*)(tp + ((size_t)q * 65536 + (size_t)y * 256 + xb * 64) * 40);
#pragma unroll
  for (int it = 0; it < 5; it++){
    int lin = it * 256 + tid;          // dword index 0..1279
    int e  = lin * 2;
    int x1 = (e * 1639) >> 16;       int c1 = e  - x1 * 40;
    int e2 = e + 1;
    int x2 = (e2 * 1639) >> 16;      int c2 = e2 - x2 * 40;
    dst[lin] = (uint)st[x1 * 41 + c1] | ((uint)st[x2 * 41 + c2] << 16);
  }
}

// =====================================================================
// Kernel 2: pack weights into MFMA A-fragment order (unchanged)
// sections (uint4 offsets): 0 dw1T,2048 cw1T,4096 w2dT,6144 w2cT,8192 w3dT,8448 w3cT
// =====================================================================
__global__ void pack_k(const float* __restrict__ dw1, const float* __restrict__ cw1,
                       const float* __restrict__ dw2, const float* __restrict__ cw2,
                       const float* __restrict__ dw3, const float* __restrict__ cw3,
                       uint4* __restrict__ wpk)
{
  int idx = blockIdx.x * 256 + threadIdx.x;
  if (idx >= 8704) return;
  int mode, rel;
  if      (idx < 2048){ mode = 0; rel = idx; }
  else if (idx < 4096){ mode = 1; rel = idx - 2048; }
  else if (idx < 6144){ mode = 2; rel = idx - 4096; }
  else if (idx < 8192){ mode = 3; rel = idx - 6144; }
  else if (idx < 8448){ mode = 4; rel = idx - 8192; }
  else                { mode = 5; rel = idx - 8448; }
  int frag = rel >> 6, lane = rel & 63;
  int Mt = frag >> 2, s = frag & 3;
  int m  = Mt * 16 + (lane & 15);
  int kb = s * 32 + (lane >> 4) * 8;
  uint d[4];
#pragma unroll
  for (int jj = 0; jj < 4; jj++){
    float v0 = 0.f, v1 = 0.f;
#pragma unroll
    for (int h = 0; h < 2; h++){
      int k = kb + jj * 2 + h;
      float v = 0.f;
      switch (mode){
        case 0: v = (k < 120) ? dw1[k * 128 + m] : 0.f; break;
        case 1: v = (k < 123) ? cw1[k * 128 + m] : 0.f; break;
        case 2: v = dw2[k * 128 + m]; break;
        case 3: v = cw2[k * 128 + m]; break;
        case 4: v = (m == 0) ? dw3[k] : 0.f; break;
        default: v = (m >= 1 && m <= 3) ? cw3[k * 3 + (m - 1)] : 0.f; break;
      }
      if (h == 0) v0 = v; else v1 = v;
    }
    d[jj] = pack2(v0, v1);
  }
  uint4 o; o.x = d[0]; o.y = d[1]; o.z = d[2]; o.w = d[3];
  wpk[idx] = o;
}

// =====================================================================
// Kernel 3: FUSED gather + MLP, 32 points/wave (t=2).
// R5: (a) launch_bounds(256,4): VGPR=80, LDS 32KB/block -> up to 5
// blocks/CU (was 2) for latency hiding; (b) LDS swizzle = +4*lrow
// rotation mod 64 dwords (bank-floor-optimal for both ds_write_b64 and
// ds_read_b128; the old XOR collided with the lq address bits -> 4-way).
// =====================================================================
__device__ __forceinline__ uint4 blend4(uint4 a, uint4 b, uint4 c, uint4 d,
                                        float w00, float w10, float w01, float w11){
  uint4 ov;
  ov.x = pack2f(w00*bflo(a.x)+w10*bflo(b.x)+w01*bflo(c.x)+w11*bflo(d.x),
                w00*bfhi(a.x)+w10*bfhi(b.x)+w01*bfhi(c.x)+w11*bfhi(d.x));
  ov.y = pack2f(w00*bflo(a.y)+w10*bflo(b.y)+w01*bflo(c.y)+w11*bflo(d.y),
                w00*bfhi(a.y)+w10*bfhi(b.y)+w01*bfhi(c.y)+w11*bfhi(d.y));
  ov.z = pack2f(w00*bflo(a.z)+w10*bflo(b.z)+w01*bflo(c.z)+w11*bflo(d.z),
                w00*bfhi(a.z)+w10*bfhi(b.z)+w01*bfhi(c.z)+w11*bfhi(d.z));
  ov.w = pack2f(w00*bflo(a.w)+w10*bflo(b.w)+w01*bflo(c.w)+w11*bflo(d.w),
                w00*bfhi(a.w)+w10*bfhi(b.w)+w01*bfhi(c.w)+w11*bfhi(d.w));
  return ov;
}

// h layout: row (t*16+lrow) has 64 dwords (128 units); unit u of a row
// lives at dword ((u>>1) + 4*lrow) & 63 (rotation swizzle).
__device__ __forceinline__ bf16x8 read_h(const uint* S, int s, int t, int lrow, int lq){
  int dwb = (s * 16 + lq * 4 + (lrow << 2)) & 63;
  return __builtin_bit_cast(bf16x8, *(const uint4*)&S[(t * 16 + lrow) * 64 + dwb]);
}

__device__ __forceinline__ void put_h(uint* S, f32x4 v, int Mt, int t, int lrow, int lq){
  uint2 w;
  w.x = pack2f(fmaxf(v[0], 0.f), fmaxf(v[1], 0.f));
  w.y = pack2f(fmaxf(v[2], 0.f), fmaxf(v[3], 0.f));
  int dw = (Mt * 8 + lq * 2 + (lrow << 2)) & 63;
  *(uint2*)&S[(t * 16 + lrow) * 64 + dw] = w;
}

__device__ __forceinline__ void layer1(uint* S, const uint4* __restrict__ W,
                                       const float* __restrict__ bias,
                                       const uint4 (&bf)[4][2],
                                       int lrow, int lq, int lane){
  f32x4 acc[8][2];
#pragma unroll
  for (int Mt = 0; Mt < 8; Mt++){
    f32x4 bi = *(const f32x4*)(bias + Mt * 16 + lq * 4);
    acc[Mt][0] = bi; acc[Mt][1] = bi;
  }
#pragma unroll
  for (int s = 0; s < 4; s++)
#pragma unroll
    for (int Mt = 0; Mt < 8; Mt++){
      bf16x8 aw = __builtin_bit_cast(bf16x8, W[(Mt * 4 + s) * 64 + lane]);
      acc[Mt][0] = MFMA16(aw, __builtin_bit_cast(bf16x8, bf[s][0]), acc[Mt][0]);
      acc[Mt][1] = MFMA16(aw, __builtin_bit_cast(bf16x8, bf[s][1]), acc[Mt][1]);
    }
#pragma unroll
  for (int Mt = 0; Mt < 8; Mt++){
    put_h(S, acc[Mt][0], Mt, 0, lrow, lq);
    put_h(S, acc[Mt][1], Mt, 1, lrow, lq);
  }
}

// dense layer: read h rows, MFMA, write h' back IN PLACE (DS pipe is
// in-order per wave; all reads issue before the writes).
__device__ __forceinline__ void dense_l(uint* S, const uint4* __restrict__ W,
                                        const float* __restrict__ bias,
                                        int lrow, int lq, int lane){
  f32x4 acc[8][2];
#pragma unroll
  for (int Mt = 0; Mt < 8; Mt++){
    f32x4 bi = *(const f32x4*)(bias + Mt * 16 + lq * 4);
    acc[Mt][0] = bi; acc[Mt][1] = bi;
  }
#pragma unroll
  for (int s = 0; s < 4; s++){
    bf16x8 bh0 = read_h(S, s, 0, lrow, lq);
    bf16x8 bh1 = read_h(S, s, 1, lrow, lq);
#pragma unroll
    for (int Mt = 0; Mt < 8; Mt++){
      bf16x8 aw = __builtin_bit_cast(bf16x8, W[(Mt * 4 + s) * 64 + lane]);
      acc[Mt][0] = MFMA16(aw, bh0, acc[Mt][0]);
      acc[Mt][1] = MFMA16(aw, bh1, acc[Mt][1]);
    }
  }
#pragma unroll
  for (int Mt = 0; Mt < 8; Mt++){
    put_h(S, acc[Mt][0], Mt, 0, lrow, lq);
    put_h(S, acc[Mt][1], Mt, 1, lrow, lq);
  }
}

__device__ __forceinline__ void out_l(const uint* S, const uint4* __restrict__ W,
                                      f32x4 (&acc3)[2], int lrow, int lq, int lane){
#pragma unroll
  for (int s = 0; s < 4; s++){
    bf16x8 aw = __builtin_bit_cast(bf16x8, W[s * 64 + lane]);
    acc3[0] = MFMA16(aw, read_h(S, s, 0, lrow, lq), acc3[0]);
    acc3[1] = MFMA16(aw, read_h(S, s, 1, lrow, lq), acc3[1]);
  }
}

__global__ __launch_bounds__(256, 4) void fused_k(
    const ushort* __restrict__ tp, const float* __restrict__ coords,
    const float* __restrict__ vdirs, const uint4* __restrict__ wpk,
    const float* __restrict__ db1, const float* __restrict__ db2,
    const float* __restrict__ db3, const float* __restrict__ cb1,
    const float* __restrict__ cb2, const float* __restrict__ cb3,
    float* __restrict__ out)
{
  __shared__ uint4 sS4[2048];   // 32 KB: 4 waves x 8 KB private
  const int wave = threadIdx.x >> 6;
  uint* S = (uint*)sS4 + wave * 2048;
  const int lane = threadIdx.x & 63, lrow = lane & 15, lq = lane >> 4;
  // batch<->XCD affinity swizzle: batch = blk&3 (XCD = blk%8 typically)
  const int blk   = blockIdx.x;                 // 0..8191
  const int pbase = (blk & 3) * 262144 + (blk >> 2) * 128 + wave * 32;

  // ---- fused gather: build B-frags directly in registers ----
  uint4 bf[4][2];
#pragma unroll
  for (int t = 0; t < 2; t++){
    const int p  = pbase + t * 16 + lrow;
    const int bb = p >> 18;                          // N = 2^18
    const float cx = coords[3 * p], cy = coords[3 * p + 1], cz = coords[3 * p + 2];
    float pw00[3], pw10[3], pw01[3], pw11[3];
    uint  o00[3], o10[3], o01[3], o11[3];
#pragma unroll
    for (int pl = 0; pl < 3; pl++){
      const float u = (pl == 2) ? cy : cx;
      const float v = (pl == 0) ? cy : cz;
      float ix = fmaf(u, 128.f, 127.5f);
      float iy = fmaf(v, 128.f, 127.5f);
      float fx0 = floorf(ix), fy0 = floorf(iy);
      float fx = ix - fx0, fy = iy - fy0;
      int x0 = (int)fx0, y0 = (int)fy0;
      float wx0 = (x0 >= 0  && x0 < 256) ? (1.f - fx) : 0.f;
      float wx1 = (x0 >= -1 && x0 < 255) ? fx : 0.f;
      float wy0 = (y0 >= 0  && y0 < 256) ? (1.f - fy) : 0.f;
      float wy1 = (y0 >= -1 && y0 < 255) ? fy : 0.f;
      int xc0 = min(max(x0, 0), 255), xc1 = min(max(x0 + 1, 0), 255);
      int yc0 = min(max(y0, 0), 255), yc1 = min(max(y0 + 1, 0), 255);
      pw00[pl] = wx0 * wy0; pw10[pl] = wx1 * wy0;
      pw01[pl] = wx0 * wy1; pw11[pl] = wx1 * wy1;
      o00[pl] = ((uint)yc0 * 256u + (uint)xc0) * 40u;
      o10[pl] = ((uint)yc0 * 256u + (uint)xc1) * 40u;
      o01[pl] = ((uint)yc1 * 256u + (uint)xc0) * 40u;
      o11[pl] = ((uint)yc1 * 256u + (uint)xc1) * 40u;
    }
#pragma unroll
    for (int s = 0; s < 4; s++){
      const int chunk = s * 4 + lq;        // channel chunk = [chunk*8, chunk*8+7]
      if (chunk == 15){                    // vd + pad (only lq==3, s==3)
        const float v0 = vdirs[3 * p], v1 = vdirs[3 * p + 1], v2 = vdirs[3 * p + 2];
        uint4 tt; tt.x = pack2f(v0, v1); tt.y = pack2f(v2, 0.f); tt.z = 0u; tt.w = 0u;
        bf[s][t] = tt;
      } else {
        const int pl = (chunk < 5) ? 0 : (chunk < 10) ? 1 : 2;
        const int c0 = chunk * 8 - pl * 40;   // local channel offset in plane row
        const ushort* base = tp + (size_t)(bb * 3 + pl) * 2621440 + c0;
        uint4 a = *(const uint4*)(base + o00[pl]);
        uint4 b = *(const uint4*)(base + o10[pl]);
        uint4 c = *(const uint4*)(base + o01[pl]);
        uint4 d = *(const uint4*)(base + o11[pl]);
        bf[s][t] = blend4(a, b, c, d, pw00[pl], pw10[pl], pw01[pl], pw11[pl]);
      }
    }
  }

  // ---- MLP ----
  f32x4 acc3[2];
  {
    float i0 = (lq == 0) ? db3[0] : 0.f;
    float i1 = (lq == 0) ? cb3[0] : 0.f;
    float i2 = (lq == 0) ? cb3[1] : 0.f;
    float i3 = (lq == 0) ? cb3[2] : 0.f;
    f32x4 iv = {i0, i1, i2, i3};
    acc3[0] = iv; acc3[1] = iv;
  }

  // density path
  layer1 (S, wpk + 0,    db1, bf, lrow, lq, lane);
  dense_l(S, wpk + 4096, db2,     lrow, lq, lane);
  out_l  (S, wpk + 8192, acc3,    lrow, lq, lane);
  // color path
  layer1 (S, wpk + 2048, cb1, bf, lrow, lq, lane);
  dense_l(S, wpk + 6144, cb2,     lrow, lq, lane);
  out_l  (S, wpk + 8448, acc3,    lrow, lq, lane);

  if (lq == 0){
#pragma unroll
    for (int t = 0; t < 2; t++){
      int p = pbase + t * 16 + lrow;
      out[p] = acc3[t][0];
      float* rgb = out + 1048576 + (size_t)p * 3;
      rgb[0] = 1.f / (1.f + __expf(-acc3[t][1]));
      rgb[1] = 1.f / (1.f + __expf(-acc3[t][2]));
      rgb[2] = 1.f / (1.f + __expf(-acc3[t][3]));
    }
  }
}

// =====================================================================
extern "C" void kernel_launch(void* const* d_in, const int* in_sizes, int n_in,
                              void* d_out, int out_size, void* d_ws, size_t ws_size,
                              hipStream_t stream)
{
  (void)in_sizes; (void)n_in; (void)out_size; (void)ws_size;
  const float* tri    = (const float*)d_in[0];
  const float* coords = (const float*)d_in[1];
  const float* vdirs  = (const float*)d_in[2];
  const float* dw1 = (const float*)d_in[3];  const float* db1 = (const float*)d_in[4];
  const float* dw2 = (const float*)d_in[5];  const float* db2 = (const float*)d_in[6];
  const float* dw3 = (const float*)d_in[7];  const float* db3 = (const float*)d_in[8];
  const float* cw1 = (const float*)d_in[9];  const float* cb1 = (const float*)d_in[10];
  const float* cw2 = (const float*)d_in[11]; const float* cb2 = (const float*)d_in[12];
  const float* cw3 = (const float*)d_in[13]; const float* cb3 = (const float*)d_in[14];

  char* ws = (char*)d_ws;
  const size_t planes_bytes = 62914560;   // 4*3*256*256*40*2
  ushort* tp  = (ushort*)ws;
  uint4*  wpk = (uint4*)(ws + planes_bytes);

  transpose_k<<<12288, 256, 0, stream>>>(tri, tp);
  pack_k<<<34, 256, 0, stream>>>(dw1, cw1, dw2, cw2, dw3, cw3, wpk);
  fused_k<<<8192, 256, 0, stream>>>(tp, coords, vdirs, wpk,
                                    db1, db2, db3, cb1, cb2, cb3,
                                    (float*)d_out);
}

// Round 6
// 663.452 us; speedup vs baseline: 1.2077x; 1.2077x over previous
//
#include <hip/hip_runtime.h>
#include <cstdint>
#include <cstddef>

typedef __bf16 bf16x8 __attribute__((ext_vector_type(8)));
typedef float  f32x4  __attribute__((ext_vector_type(4)));

#define MFMA16(a,b,c) __builtin_amdgcn_mfma_f32_16x16x32_bf16((a),(b),(c),0,0,0)

// ---------- helpers ----------
__device__ __forceinline__ uint f2bf1(float f){
  uint u = __builtin_bit_cast(uint, f);
  u += 0x7FFFu + ((u >> 16) & 1u);   // RNE to bf16
  return u >> 16;
}
__device__ __forceinline__ uint pack2(float a, float b){  // RNE (cold paths)
  return f2bf1(a) | (f2bf1(b) << 16);
}
// fast pack: round-half-away via biased add + v_perm_b32 (3 VALU ops)
__device__ __forceinline__ uint pack2f(float a, float b){
  uint ua = __builtin_bit_cast(uint, a) + 0x8000u;
  uint ub = __builtin_bit_cast(uint, b) + 0x8000u;
  return __builtin_amdgcn_perm(ub, ua, 0x07060302u); // {ua.b2,ua.b3,ub.b2,ub.b3}
}
__device__ __forceinline__ float bflo(uint d){ return __builtin_bit_cast(float, d << 16); }
__device__ __forceinline__ float bfhi(uint d){ return __builtin_bit_cast(float, d & 0xFFFF0000u); }

// =====================================================================
// Kernel 1: transpose triplane (B,3,C,H,W) fp32 -> (B,3,H,W,C) bf16
// =====================================================================
__global__ __launch_bounds__(256, 4) void transpose_k(
    const float* __restrict__ tri, ushort* __restrict__ tp)
{
  __shared__ ushort st[64 * 41];
  const int bi  = blockIdx.x;
  const int xb  = bi & 3;
  const int y   = (bi >> 2) & 255;
  const int q   = bi >> 10;            // b*3+pl, 0..11
  const int tid = threadIdx.x;
  const float* src = tri + (size_t)q * 40 * 65536 + y * 256 + xb * 64;
#pragma unroll
  for (int it = 0; it < 10; it++){
    int lin = it * 256 + tid;          // 0..2559
    int c = lin >> 6, x = lin & 63;
    float v = src[(size_t)c * 65536 + x];
    st[x * 41 + c] = (ushort)f2bf1(v);
  }
  __syncthreads();
  uint* dst = (uint*)(tp + ((size_t)q * 65536 + (size_t)y * 256 + xb * 64) * 40);
#pragma unroll
  for (int it = 0; it < 5; it++){
    int lin = it * 256 + tid;          // dword index 0..1279
    int e  = lin * 2;
    int x1 = (e * 1639) >> 16;       int c1 = e  - x1 * 40;
    int e2 = e + 1;
    int x2 = (e2 * 1639) >> 16;      int c2 = e2 - x2 * 40;
    dst[lin] = (uint)st[x1 * 41 + c1] | ((uint)st[x2 * 41 + c2] << 16);
  }
}

// =====================================================================
// Kernel 2: pack weights into MFMA A-fragment order (unchanged)
// sections (uint4 offsets): 0 dw1T,2048 cw1T,4096 w2dT,6144 w2cT,8192 w3dT,8448 w3cT
// =====================================================================
__global__ void pack_k(const float* __restrict__ dw1, const float* __restrict__ cw1,
                       const float* __restrict__ dw2, const float* __restrict__ cw2,
                       const float* __restrict__ dw3, const float* __restrict__ cw3,
                       uint4* __restrict__ wpk)
{
  int idx = blockIdx.x * 256 + threadIdx.x;
  if (idx >= 8704) return;
  int mode, rel;
  if      (idx < 2048){ mode = 0; rel = idx; }
  else if (idx < 4096){ mode = 1; rel = idx - 2048; }
  else if (idx < 6144){ mode = 2; rel = idx - 4096; }
  else if (idx < 8192){ mode = 3; rel = idx - 6144; }
  else if (idx < 8448){ mode = 4; rel = idx - 8192; }
  else                { mode = 5; rel = idx - 8448; }
  int frag = rel >> 6, lane = rel & 63;
  int Mt = frag >> 2, s = frag & 3;
  int m  = Mt * 16 + (lane & 15);
  int kb = s * 32 + (lane >> 4) * 8;
  uint d[4];
#pragma unroll
  for (int jj = 0; jj < 4; jj++){
    float v0 = 0.f, v1 = 0.f;
#pragma unroll
    for (int h = 0; h < 2; h++){
      int k = kb + jj * 2 + h;
      float v = 0.f;
      switch (mode){
        case 0: v = (k < 120) ? dw1[k * 128 + m] : 0.f; break;
        case 1: v = (k < 123) ? cw1[k * 128 + m] : 0.f; break;
        case 2: v = dw2[k * 128 + m]; break;
        case 3: v = cw2[k * 128 + m]; break;
        case 4: v = (m == 0) ? dw3[k] : 0.f; break;
        default: v = (m >= 1 && m <= 3) ? cw3[k * 3 + (m - 1)] : 0.f; break;
      }
      if (h == 0) v0 = v; else v1 = v;
    }
    d[jj] = pack2(v0, v1);
  }
  uint4 o; o.x = d[0]; o.y = d[1]; o.z = d[2]; o.w = d[3];
  wpk[idx] = o;
}

// =====================================================================
// Kernel 3: FUSED gather + MLP, 32 points/wave (t=2).
// R6: launch_bounds(256,3) — the measured sweet spot:
//   (256,2): no spill, 8 waves/CU, 541 us (latency-bound)   [R4]
//   (256,4): 128-reg budget < ~144-reg demand -> spills, 600 us [R5]
//   (256,3): 170-reg budget >= demand -> no spill, 12 waves/CU.
// LDS: 8 KB/wave, wave-private, rotation swizzle (+4*lrow mod 64 dwords).
// =====================================================================
__device__ __forceinline__ uint4 blend4(uint4 a, uint4 b, uint4 c, uint4 d,
                                        float w00, float w10, float w01, float w11){
  uint4 ov;
  ov.x = pack2f(w00*bflo(a.x)+w10*bflo(b.x)+w01*bflo(c.x)+w11*bflo(d.x),
                w00*bfhi(a.x)+w10*bfhi(b.x)+w01*bfhi(c.x)+w11*bfhi(d.x));
  ov.y = pack2f(w00*bflo(a.y)+w10*bflo(b.y)+w01*bflo(c.y)+w11*bflo(d.y),
                w00*bfhi(a.y)+w10*bfhi(b.y)+w01*bfhi(c.y)+w11*bfhi(d.y));
  ov.z = pack2f(w00*bflo(a.z)+w10*bflo(b.z)+w01*bflo(c.z)+w11*bflo(d.z),
                w00*bfhi(a.z)+w10*bfhi(b.z)+w01*bfhi(c.z)+w11*bfhi(d.z));
  ov.w = pack2f(w00*bflo(a.w)+w10*bflo(b.w)+w01*bflo(c.w)+w11*bflo(d.w),
                w00*bfhi(a.w)+w10*bfhi(b.w)+w01*bfhi(c.w)+w11*bfhi(d.w));
  return ov;
}

// h layout: row (t*16+lrow) has 64 dwords (128 units); unit u of a row
// lives at dword ((u>>1) + 4*lrow) & 63 (rotation swizzle).
__device__ __forceinline__ bf16x8 read_h(const uint* S, int s, int t, int lrow, int lq){
  int dwb = (s * 16 + lq * 4 + (lrow << 2)) & 63;
  return __builtin_bit_cast(bf16x8, *(const uint4*)&S[(t * 16 + lrow) * 64 + dwb]);
}

__device__ __forceinline__ void put_h(uint* S, f32x4 v, int Mt, int t, int lrow, int lq){
  uint2 w;
  w.x = pack2f(fmaxf(v[0], 0.f), fmaxf(v[1], 0.f));
  w.y = pack2f(fmaxf(v[2], 0.f), fmaxf(v[3], 0.f));
  int dw = (Mt * 8 + lq * 2 + (lrow << 2)) & 63;
  *(uint2*)&S[(t * 16 + lrow) * 64 + dw] = w;
}

__device__ __forceinline__ void layer1(uint* S, const uint4* __restrict__ W,
                                       const float* __restrict__ bias,
                                       const uint4 (&bf)[4][2],
                                       int lrow, int lq, int lane){
  f32x4 acc[8][2];
#pragma unroll
  for (int Mt = 0; Mt < 8; Mt++){
    f32x4 bi = *(const f32x4*)(bias + Mt * 16 + lq * 4);
    acc[Mt][0] = bi; acc[Mt][1] = bi;
  }
#pragma unroll
  for (int s = 0; s < 4; s++)
#pragma unroll
    for (int Mt = 0; Mt < 8; Mt++){
      bf16x8 aw = __builtin_bit_cast(bf16x8, W[(Mt * 4 + s) * 64 + lane]);
      acc[Mt][0] = MFMA16(aw, __builtin_bit_cast(bf16x8, bf[s][0]), acc[Mt][0]);
      acc[Mt][1] = MFMA16(aw, __builtin_bit_cast(bf16x8, bf[s][1]), acc[Mt][1]);
    }
#pragma unroll
  for (int Mt = 0; Mt < 8; Mt++){
    put_h(S, acc[Mt][0], Mt, 0, lrow, lq);
    put_h(S, acc[Mt][1], Mt, 1, lrow, lq);
  }
}

// dense layer: read h rows, MFMA, write h' back IN PLACE (DS pipe is
// in-order per wave; all reads issue before the writes).
__device__ __forceinline__ void dense_l(uint* S, const uint4* __restrict__ W,
                                        const float* __restrict__ bias,
                                        int lrow, int lq, int lane){
  f32x4 acc[8][2];
#pragma unroll
  for (int Mt = 0; Mt < 8; Mt++){
    f32x4 bi = *(const f32x4*)(bias + Mt * 16 + lq * 4);
    acc[Mt][0] = bi; acc[Mt][1] = bi;
  }
#pragma unroll
  for (int s = 0; s < 4; s++){
    bf16x8 bh0 = read_h(S, s, 0, lrow, lq);
    bf16x8 bh1 = read_h(S, s, 1, lrow, lq);
#pragma unroll
    for (int Mt = 0; Mt < 8; Mt++){
      bf16x8 aw = __builtin_bit_cast(bf16x8, W[(Mt * 4 + s) * 64 + lane]);
      acc[Mt][0] = MFMA16(aw, bh0, acc[Mt][0]);
      acc[Mt][1] = MFMA16(aw, bh1, acc[Mt][1]);
    }
  }
#pragma unroll
  for (int Mt = 0; Mt < 8; Mt++){
    put_h(S, acc[Mt][0], Mt, 0, lrow, lq);
    put_h(S, acc[Mt][1], Mt, 1, lrow, lq);
  }
}

__device__ __forceinline__ void out_l(const uint* S, const uint4* __restrict__ W,
                                      f32x4 (&acc3)[2], int lrow, int lq, int lane){
#pragma unroll
  for (int s = 0; s < 4; s++){
    bf16x8 aw = __builtin_bit_cast(bf16x8, W[s * 64 + lane]);
    acc3[0] = MFMA16(aw, read_h(S, s, 0, lrow, lq), acc3[0]);
    acc3[1] = MFMA16(aw, read_h(S, s, 1, lrow, lq), acc3[1]);
  }
}

__global__ __launch_bounds__(256, 3) void fused_k(
    const ushort* __restrict__ tp, const float* __restrict__ coords,
    const float* __restrict__ vdirs, const uint4* __restrict__ wpk,
    const float* __restrict__ db1, const float* __restrict__ db2,
    const float* __restrict__ db3, const float* __restrict__ cb1,
    const float* __restrict__ cb2, const float* __restrict__ cb3,
    float* __restrict__ out)
{
  __shared__ uint4 sS4[2048];   // 32 KB: 4 waves x 8 KB private
  const int wave = threadIdx.x >> 6;
  uint* S = (uint*)sS4 + wave * 2048;
  const int lane = threadIdx.x & 63, lrow = lane & 15, lq = lane >> 4;
  // batch<->XCD affinity swizzle: batch = blk&3 (XCD = blk%8 typically)
  const int blk   = blockIdx.x;                 // 0..8191
  const int pbase = (blk & 3) * 262144 + (blk >> 2) * 128 + wave * 32;

  // ---- fused gather: build B-frags directly in registers ----
  uint4 bf[4][2];
#pragma unroll
  for (int t = 0; t < 2; t++){
    const int p  = pbase + t * 16 + lrow;
    const int bb = p >> 18;                          // N = 2^18
    const float cx = coords[3 * p], cy = coords[3 * p + 1], cz = coords[3 * p + 2];
    float pw00[3], pw10[3], pw01[3], pw11[3];
    uint  o00[3], o10[3], o01[3], o11[3];
#pragma unroll
    for (int pl = 0; pl < 3; pl++){
      const float u = (pl == 2) ? cy : cx;
      const float v = (pl == 0) ? cy : cz;
      float ix = fmaf(u, 128.f, 127.5f);
      float iy = fmaf(v, 128.f, 127.5f);
      float fx0 = floorf(ix), fy0 = floorf(iy);
      float fx = ix - fx0, fy = iy - fy0;
      int x0 = (int)fx0, y0 = (int)fy0;
      float wx0 = (x0 >= 0  && x0 < 256) ? (1.f - fx) : 0.f;
      float wx1 = (x0 >= -1 && x0 < 255) ? fx : 0.f;
      float wy0 = (y0 >= 0  && y0 < 256) ? (1.f - fy) : 0.f;
      float wy1 = (y0 >= -1 && y0 < 255) ? fy : 0.f;
      int xc0 = min(max(x0, 0), 255), xc1 = min(max(x0 + 1, 0), 255);
      int yc0 = min(max(y0, 0), 255), yc1 = min(max(y0 + 1, 0), 255);
      pw00[pl] = wx0 * wy0; pw10[pl] = wx1 * wy0;
      pw01[pl] = wx0 * wy1; pw11[pl] = wx1 * wy1;
      o00[pl] = ((uint)yc0 * 256u + (uint)xc0) * 40u;
      o10[pl] = ((uint)yc0 * 256u + (uint)xc1) * 40u;
      o01[pl] = ((uint)yc1 * 256u + (uint)xc0) * 40u;
      o11[pl] = ((uint)yc1 * 256u + (uint)xc1) * 40u;
    }
#pragma unroll
    for (int s = 0; s < 4; s++){
      const int chunk = s * 4 + lq;        // channel chunk = [chunk*8, chunk*8+7]
      if (chunk == 15){                    // vd + pad (only lq==3, s==3)
        const float v0 = vdirs[3 * p], v1 = vdirs[3 * p + 1], v2 = vdirs[3 * p + 2];
        uint4 tt; tt.x = pack2f(v0, v1); tt.y = pack2f(v2, 0.f); tt.z = 0u; tt.w = 0u;
        bf[s][t] = tt;
      } else {
        const int pl = (chunk < 5) ? 0 : (chunk < 10) ? 1 : 2;
        const int c0 = chunk * 8 - pl * 40;   // local channel offset in plane row
        const ushort* base = tp + (size_t)(bb * 3 + pl) * 2621440 + c0;
        uint4 a = *(const uint4*)(base + o00[pl]);
        uint4 b = *(const uint4*)(base + o10[pl]);
        uint4 c = *(const uint4*)(base + o01[pl]);
        uint4 d = *(const uint4*)(base + o11[pl]);
        bf[s][t] = blend4(a, b, c, d, pw00[pl], pw10[pl], pw01[pl], pw11[pl]);
      }
    }
  }

  // ---- MLP ----
  f32x4 acc3[2];
  {
    float i0 = (lq == 0) ? db3[0] : 0.f;
    float i1 = (lq == 0) ? cb3[0] : 0.f;
    float i2 = (lq == 0) ? cb3[1] : 0.f;
    float i3 = (lq == 0) ? cb3[2] : 0.f;
    f32x4 iv = {i0, i1, i2, i3};
    acc3[0] = iv; acc3[1] = iv;
  }

  // density path
  layer1 (S, wpk + 0,    db1, bf, lrow, lq, lane);
  dense_l(S, wpk + 4096, db2,     lrow, lq, lane);
  out_l  (S, wpk + 8192, acc3,    lrow, lq, lane);
  // color path
  layer1 (S, wpk + 2048, cb1, bf, lrow, lq, lane);
  dense_l(S, wpk + 6144, cb2,     lrow, lq, lane);
  out_l  (S, wpk + 8448, acc3,    lrow, lq, lane);

  if (lq == 0){
#pragma unroll
    for (int t = 0; t < 2; t++){
      int p = pbase + t * 16 + lrow;
      out[p] = acc3[t][0];
      float* rgb = out + 1048576 + (size_t)p * 3;
      rgb[0] = 1.f / (1.f + __expf(-acc3[t][1]));
      rgb[1] = 1.f / (1.f + __expf(-acc3[t][2]));
      rgb[2] = 1.f / (1.f + __expf(-acc3[t][3]));
    }
  }
}

// =====================================================================
extern "C" void kernel_launch(void* const* d_in, const int* in_sizes, int n_in,
                              void* d_out, int out_size, void* d_ws, size_t ws_size,
                              hipStream_t stream)
{
  (void)in_sizes; (void)n_in; (void)out_size; (void)ws_size;
  const float* tri    = (const float*)d_in[0];
  const float* coords = (const float*)d_in[1];
  const float* vdirs  = (const float*)d_in[2];
  const float* dw1 = (const float*)d_in[3];  const float* db1 = (const float*)d_in[4];
  const float* dw2 = (const float*)d_in[5];  const float* db2 = (const float*)d_in[6];
  const float* dw3 = (const float*)d_in[7];  const float* db3 = (const float*)d_in[8];
  const float* cw1 = (const float*)d_in[9];  const float* cb1 = (const float*)d_in[10];
  const float* cw2 = (const float*)d_in[11]; const float* cb2 = (const float*)d_in[12];
  const float* cw3 = (const float*)d_in[13]; const float* cb3 = (const float*)d_in[14];

  char* ws = (char*)d_ws;
  const size_t planes_bytes = 62914560;   // 4*3*256*256*40*2
  ushort* tp  = (ushort*)ws;
  uint4*  wpk = (uint4*)(ws + planes_bytes);

  transpose_k<<<12288, 256, 0, stream>>>(tri, tp);
  pack_k<<<34, 256, 0, stream>>>(dw1, cw1, dw2, cw2, dw3, cw3, wpk);
  fused_k<<<8192, 256, 0, stream>>>(tp, coords, vdirs, wpk,
                                    db1, db2, db3, cb1, cb2, cb3,
                                    (float*)d_out);
}

// Round 7
// 643.746 us; speedup vs baseline: 1.2446x; 1.0306x over previous
//
#include <hip/hip_runtime.h>
#include <cstdint>
#include <cstddef>

typedef __bf16 bf16x8 __attribute__((ext_vector_type(8)));
typedef float  f32x4  __attribute__((ext_vector_type(4)));

#define MFMA16(a,b,c) __builtin_amdgcn_mfma_f32_16x16x32_bf16((a),(b),(c),0,0,0)

// ---------- helpers ----------
__device__ __forceinline__ uint f2bf1(float f){
  uint u = __builtin_bit_cast(uint, f);
  u += 0x7FFFu + ((u >> 16) & 1u);   // RNE to bf16
  return u >> 16;
}
__device__ __forceinline__ uint pack2(float a, float b){  // RNE (cold paths)
  return f2bf1(a) | (f2bf1(b) << 16);
}
// fast pack: round-half-away via biased add + v_perm_b32 (3 VALU ops)
__device__ __forceinline__ uint pack2f(float a, float b){
  uint ua = __builtin_bit_cast(uint, a) + 0x8000u;
  uint ub = __builtin_bit_cast(uint, b) + 0x8000u;
  return __builtin_amdgcn_perm(ub, ua, 0x07060302u); // {ua.b2,ua.b3,ub.b2,ub.b3}
}
__device__ __forceinline__ float bflo(uint d){ return __builtin_bit_cast(float, d << 16); }
__device__ __forceinline__ float bfhi(uint d){ return __builtin_bit_cast(float, d & 0xFFFF0000u); }

// =====================================================================
// Kernel 1 (merged): blocks [0,12288) transpose triplane fp32->bf16
// (B,3,C,H,W)->(B,3,H,W,C); blocks [12288,12322) pack weights into
// MFMA A-frag order. Merged to remove one launch gap.
// sections (uint4 offsets): 0 dw1T,2048 cw1T,4096 w2dT,6144 w2cT,8192 w3dT,8448 w3cT
// =====================================================================
__global__ __launch_bounds__(256, 4) void prep_k(
    const float* __restrict__ tri, ushort* __restrict__ tp,
    const float* __restrict__ dw1, const float* __restrict__ cw1,
    const float* __restrict__ dw2, const float* __restrict__ cw2,
    const float* __restrict__ dw3, const float* __restrict__ cw3,
    uint4* __restrict__ wpk)
{
  __shared__ ushort st[64 * 41];
  const int tid = threadIdx.x;
  if (blockIdx.x < 12288){
    const int bi  = blockIdx.x;
    const int xb  = bi & 3;
    const int y   = (bi >> 2) & 255;
    const int q   = bi >> 10;            // b*3+pl, 0..11
    const float* src = tri + (size_t)q * 40 * 65536 + y * 256 + xb * 64;
#pragma unroll
    for (int it = 0; it < 10; it++){
      int lin = it * 256 + tid;          // 0..2559
      int c = lin >> 6, x = lin & 63;
      float v = src[(size_t)c * 65536 + x];
      st[x * 41 + c] = (ushort)f2bf1(v);
    }
    __syncthreads();
    uint* dst = (uint*)(tp + ((size_t)q * 65536 + (size_t)y * 256 + xb * 64) * 40);
#pragma unroll
    for (int it = 0; it < 5; it++){
      int lin = it * 256 + tid;          // dword index 0..1279
      int e  = lin * 2;
      int x1 = (e * 1639) >> 16;       int c1 = e  - x1 * 40;
      int e2 = e + 1;
      int x2 = (e2 * 1639) >> 16;      int c2 = e2 - x2 * 40;
      dst[lin] = (uint)st[x1 * 41 + c1] | ((uint)st[x2 * 41 + c2] << 16);
    }
  } else {
    int idx = (blockIdx.x - 12288) * 256 + tid;
    if (idx >= 8704) return;
    int mode, rel;
    if      (idx < 2048){ mode = 0; rel = idx; }
    else if (idx < 4096){ mode = 1; rel = idx - 2048; }
    else if (idx < 6144){ mode = 2; rel = idx - 4096; }
    else if (idx < 8192){ mode = 3; rel = idx - 6144; }
    else if (idx < 8448){ mode = 4; rel = idx - 8192; }
    else                { mode = 5; rel = idx - 8448; }
    int frag = rel >> 6, lane = rel & 63;
    int Mt = frag >> 2, s = frag & 3;
    int m  = Mt * 16 + (lane & 15);
    int kb = s * 32 + (lane >> 4) * 8;
    uint d[4];
#pragma unroll
    for (int jj = 0; jj < 4; jj++){
      float v0 = 0.f, v1 = 0.f;
#pragma unroll
      for (int h = 0; h < 2; h++){
        int k = kb + jj * 2 + h;
        float v = 0.f;
        switch (mode){
          case 0: v = (k < 120) ? dw1[k * 128 + m] : 0.f; break;
          case 1: v = (k < 123) ? cw1[k * 128 + m] : 0.f; break;
          case 2: v = dw2[k * 128 + m]; break;
          case 3: v = cw2[k * 128 + m]; break;
          case 4: v = (m == 0) ? dw3[k] : 0.f; break;
          default: v = (m >= 1 && m <= 3) ? cw3[k * 3 + (m - 1)] : 0.f; break;
        }
        if (h == 0) v0 = v; else v1 = v;
      }
      d[jj] = pack2(v0, v1);
    }
    uint4 o; o.x = d[0]; o.y = d[1]; o.z = d[2]; o.w = d[3];
    wpk[idx] = o;
  }
}

// =====================================================================
// Kernel 2: FUSED gather + MLP, 512 thr (8 waves x 32 points), weights
// streamed per-layer into a 2x32KB LDS double-buffer via async
// global_load_lds (prefetch for phase k+1 issued at start of phase k;
// __syncthreads' vmcnt-drain before s_barrier guarantees completion).
// Weight reads become ds_read_b128 -> VMEM pipe freed for the gather.
// LDS: 64KB h-staging (8KB/wave private) + 64KB weight dbuf = 128KB dyn.
// =====================================================================
__device__ __forceinline__ void stage_w(const uint4* __restrict__ g,
                                        uint4* l, int wave, int lane, int n){
  // block-cooperative copy of n uint4 (n % 64 == 0), 8 waves, async to LDS
  const int chunks = n >> 6;                    // 1KB chunks (64 uint4)
  for (int c = wave; c < chunks; c += 8){
    __builtin_amdgcn_global_load_lds(
      (const __attribute__((address_space(1))) void*)(g + c * 64 + lane),
      (__attribute__((address_space(3))) void*)(l + c * 64 + lane),
      16, 0, 0);
  }
}

__device__ __forceinline__ uint4 blend4(uint4 a, uint4 b, uint4 c, uint4 d,
                                        float w00, float w10, float w01, float w11){
  uint4 ov;
  ov.x = pack2f(w00*bflo(a.x)+w10*bflo(b.x)+w01*bflo(c.x)+w11*bflo(d.x),
                w00*bfhi(a.x)+w10*bfhi(b.x)+w01*bfhi(c.x)+w11*bfhi(d.x));
  ov.y = pack2f(w00*bflo(a.y)+w10*bflo(b.y)+w01*bflo(c.y)+w11*bflo(d.y),
                w00*bfhi(a.y)+w10*bfhi(b.y)+w01*bfhi(c.y)+w11*bfhi(d.y));
  ov.z = pack2f(w00*bflo(a.z)+w10*bflo(b.z)+w01*bflo(c.z)+w11*bflo(d.z),
                w00*bfhi(a.z)+w10*bfhi(b.z)+w01*bfhi(c.z)+w11*bfhi(d.z));
  ov.w = pack2f(w00*bflo(a.w)+w10*bflo(b.w)+w01*bflo(c.w)+w11*bflo(d.w),
                w00*bfhi(a.w)+w10*bfhi(b.w)+w01*bfhi(c.w)+w11*bfhi(d.w));
  return ov;
}

// h layout: row (t*16+lrow) has 64 dwords (128 units); rotation swizzle.
__device__ __forceinline__ bf16x8 read_h(const uint* S, int s, int t, int lrow, int lq){
  int dwb = (s * 16 + lq * 4 + (lrow << 2)) & 63;
  return __builtin_bit_cast(bf16x8, *(const uint4*)&S[(t * 16 + lrow) * 64 + dwb]);
}

__device__ __forceinline__ void put_h(uint* S, f32x4 v, int Mt, int t, int lrow, int lq){
  uint2 w;
  w.x = pack2f(fmaxf(v[0], 0.f), fmaxf(v[1], 0.f));
  w.y = pack2f(fmaxf(v[2], 0.f), fmaxf(v[3], 0.f));
  int dw = (Mt * 8 + lq * 2 + (lrow << 2)) & 63;
  *(uint2*)&S[(t * 16 + lrow) * 64 + dw] = w;
}

__device__ __forceinline__ void layer1(uint* S, const uint4* W,
                                       const float* __restrict__ bias,
                                       const uint4 (&bf)[4][2],
                                       int lrow, int lq, int lane){
  f32x4 acc[8][2];
#pragma unroll
  for (int Mt = 0; Mt < 8; Mt++){
    f32x4 bi = *(const f32x4*)(bias + Mt * 16 + lq * 4);
    acc[Mt][0] = bi; acc[Mt][1] = bi;
  }
#pragma unroll
  for (int s = 0; s < 4; s++)
#pragma unroll
    for (int Mt = 0; Mt < 8; Mt++){
      bf16x8 aw = __builtin_bit_cast(bf16x8, W[(Mt * 4 + s) * 64 + lane]);
      acc[Mt][0] = MFMA16(aw, __builtin_bit_cast(bf16x8, bf[s][0]), acc[Mt][0]);
      acc[Mt][1] = MFMA16(aw, __builtin_bit_cast(bf16x8, bf[s][1]), acc[Mt][1]);
    }
#pragma unroll
  for (int Mt = 0; Mt < 8; Mt++){
    put_h(S, acc[Mt][0], Mt, 0, lrow, lq);
    put_h(S, acc[Mt][1], Mt, 1, lrow, lq);
  }
}

// dense layer: read h rows, MFMA, write h' back IN PLACE (per-wave DS
// ordering: all reads issue before the writes).
__device__ __forceinline__ void dense_l(uint* S, const uint4* W,
                                        const float* __restrict__ bias,
                                        int lrow, int lq, int lane){
  f32x4 acc[8][2];
#pragma unroll
  for (int Mt = 0; Mt < 8; Mt++){
    f32x4 bi = *(const f32x4*)(bias + Mt * 16 + lq * 4);
    acc[Mt][0] = bi; acc[Mt][1] = bi;
  }
#pragma unroll
  for (int s = 0; s < 4; s++){
    bf16x8 bh0 = read_h(S, s, 0, lrow, lq);
    bf16x8 bh1 = read_h(S, s, 1, lrow, lq);
#pragma unroll
    for (int Mt = 0; Mt < 8; Mt++){
      bf16x8 aw = __builtin_bit_cast(bf16x8, W[(Mt * 4 + s) * 64 + lane]);
      acc[Mt][0] = MFMA16(aw, bh0, acc[Mt][0]);
      acc[Mt][1] = MFMA16(aw, bh1, acc[Mt][1]);
    }
  }
#pragma unroll
  for (int Mt = 0; Mt < 8; Mt++){
    put_h(S, acc[Mt][0], Mt, 0, lrow, lq);
    put_h(S, acc[Mt][1], Mt, 1, lrow, lq);
  }
}

__device__ __forceinline__ void out_l(const uint* S, const uint4* W,
                                      f32x4 (&acc3)[2], int lrow, int lq, int lane){
#pragma unroll
  for (int s = 0; s < 4; s++){
    bf16x8 aw = __builtin_bit_cast(bf16x8, W[s * 64 + lane]);
    acc3[0] = MFMA16(aw, read_h(S, s, 0, lrow, lq), acc3[0]);
    acc3[1] = MFMA16(aw, read_h(S, s, 1, lrow, lq), acc3[1]);
  }
}

__global__ __launch_bounds__(512, 2) void fused_k(
    const ushort* __restrict__ tp, const float* __restrict__ coords,
    const float* __restrict__ vdirs, const uint4* __restrict__ wpk,
    const float* __restrict__ db1, const float* __restrict__ db2,
    const float* __restrict__ db3, const float* __restrict__ cb1,
    const float* __restrict__ cb2, const float* __restrict__ cb3,
    float* __restrict__ out)
{
  extern __shared__ uint4 smem[];               // 8192 uint4 = 128 KB
  const int wave = threadIdx.x >> 6;            // 0..7
  uint*  S   = (uint*)(smem + (size_t)wave * 512);  // 8 KB wave-private h
  uint4* WB0 = smem + 4096;                     // 32 KB weight buf 0
  uint4* WB1 = smem + 6144;                     // 32 KB weight buf 1
  const int lane = threadIdx.x & 63, lrow = lane & 15, lq = lane >> 4;
  // batch<->XCD affinity: XCD = blk%8 => batch = blk&3 pins one batch/XCD
  const int blk   = blockIdx.x;                 // 0..4095
  const int pbase = (blk & 3) * 262144 + (blk >> 2) * 256 + wave * 32;

  stage_w(wpk + 0, WB0, wave, lane, 2048);      // prefetch w1d (under gather)

  // ---- fused gather: build B-frags directly in registers ----
  uint4 bf[4][2];
#pragma unroll
  for (int t = 0; t < 2; t++){
    const int p  = pbase + t * 16 + lrow;
    const int bb = p >> 18;                          // N = 2^18
    const float cx = coords[3 * p], cy = coords[3 * p + 1], cz = coords[3 * p + 2];
    float pw00[3], pw10[3], pw01[3], pw11[3];
    uint  o00[3], o10[3], o01[3], o11[3];
#pragma unroll
    for (int pl = 0; pl < 3; pl++){
      const float u = (pl == 2) ? cy : cx;
      const float v = (pl == 0) ? cy : cz;
      float ix = fmaf(u, 128.f, 127.5f);
      float iy = fmaf(v, 128.f, 127.5f);
      float fx0 = floorf(ix), fy0 = floorf(iy);
      float fx = ix - fx0, fy = iy - fy0;
      int x0 = (int)fx0, y0 = (int)fy0;
      float wx0 = (x0 >= 0  && x0 < 256) ? (1.f - fx) : 0.f;
      float wx1 = (x0 >= -1 && x0 < 255) ? fx : 0.f;
      float wy0 = (y0 >= 0  && y0 < 256) ? (1.f - fy) : 0.f;
      float wy1 = (y0 >= -1 && y0 < 255) ? fy : 0.f;
      int xc0 = min(max(x0, 0), 255), xc1 = min(max(x0 + 1, 0), 255);
      int yc0 = min(max(y0, 0), 255), yc1 = min(max(y0 + 1, 0), 255);
      pw00[pl] = wx0 * wy0; pw10[pl] = wx1 * wy0;
      pw01[pl] = wx0 * wy1; pw11[pl] = wx1 * wy1;
      o00[pl] = ((uint)yc0 * 256u + (uint)xc0) * 40u;
      o10[pl] = ((uint)yc0 * 256u + (uint)xc1) * 40u;
      o01[pl] = ((uint)yc1 * 256u + (uint)xc0) * 40u;
      o11[pl] = ((uint)yc1 * 256u + (uint)xc1) * 40u;
    }
#pragma unroll
    for (int s = 0; s < 4; s++){
      const int chunk = s * 4 + lq;        // channel chunk = [chunk*8, chunk*8+7]
      if (chunk == 15){                    // vd + pad (only lq==3, s==3)
        const float v0 = vdirs[3 * p], v1 = vdirs[3 * p + 1], v2 = vdirs[3 * p + 2];
        uint4 tt; tt.x = pack2f(v0, v1); tt.y = pack2f(v2, 0.f); tt.z = 0u; tt.w = 0u;
        bf[s][t] = tt;
      } else {
        const int pl = (chunk < 5) ? 0 : (chunk < 10) ? 1 : 2;
        const int c0 = chunk * 8 - pl * 40;   // local channel offset in plane row
        const ushort* base = tp + (size_t)(bb * 3 + pl) * 2621440 + c0;
        uint4 a = *(const uint4*)(base + o00[pl]);
        uint4 b = *(const uint4*)(base + o10[pl]);
        uint4 c = *(const uint4*)(base + o01[pl]);
        uint4 d = *(const uint4*)(base + o11[pl]);
        bf[s][t] = blend4(a, b, c, d, pw00[pl], pw10[pl], pw01[pl], pw11[pl]);
      }
    }
  }

  f32x4 acc3[2];
  {
    float i0 = (lq == 0) ? db3[0] : 0.f;
    float i1 = (lq == 0) ? cb3[0] : 0.f;
    float i2 = (lq == 0) ? cb3[1] : 0.f;
    float i3 = (lq == 0) ? cb3[2] : 0.f;
    f32x4 iv = {i0, i1, i2, i3};
    acc3[0] = iv; acc3[1] = iv;
  }

  __syncthreads();                               // w1d ready

  stage_w(wpk + 4096, WB1, wave, lane, 2048);    // prefetch w2d
  layer1 (S, WB0, db1, bf, lrow, lq, lane);      // feats -> h1d
  __syncthreads();                               // w2d ready; WB0 free

  stage_w(wpk + 8192, WB0, wave, lane, 256);     // prefetch w3d
  dense_l(S, WB1, db2, lrow, lq, lane);          // h1d -> h2d
  __syncthreads();                               // w3d ready; WB1 free

  stage_w(wpk + 2048, WB1, wave, lane, 2048);    // prefetch w1c
  out_l  (S, WB0, acc3, lrow, lq, lane);         // h2d -> density
  __syncthreads();                               // w1c ready; WB0 free

  stage_w(wpk + 6144, WB0, wave, lane, 2048);    // prefetch w2c
  layer1 (S, WB1, cb1, bf, lrow, lq, lane);      // feats -> h1c
  __syncthreads();                               // w2c ready; WB1 free

  stage_w(wpk + 8448, WB1, wave, lane, 256);     // prefetch w3c
  dense_l(S, WB0, cb2, lrow, lq, lane);          // h1c -> h2c
  __syncthreads();                               // w3c ready

  out_l  (S, WB1, acc3, lrow, lq, lane);         // h2c -> rgb

  if (lq == 0){
#pragma unroll
    for (int t = 0; t < 2; t++){
      int p = pbase + t * 16 + lrow;
      out[p] = acc3[t][0];
      float* rgb = out + 1048576 + (size_t)p * 3;
      rgb[0] = 1.f / (1.f + __expf(-acc3[t][1]));
      rgb[1] = 1.f / (1.f + __expf(-acc3[t][2]));
      rgb[2] = 1.f / (1.f + __expf(-acc3[t][3]));
    }
  }
}

// =====================================================================
extern "C" void kernel_launch(void* const* d_in, const int* in_sizes, int n_in,
                              void* d_out, int out_size, void* d_ws, size_t ws_size,
                              hipStream_t stream)
{
  (void)in_sizes; (void)n_in; (void)out_size; (void)ws_size;
  const float* tri    = (const float*)d_in[0];
  const float* coords = (const float*)d_in[1];
  const float* vdirs  = (const float*)d_in[2];
  const float* dw1 = (const float*)d_in[3];  const float* db1 = (const float*)d_in[4];
  const float* dw2 = (const float*)d_in[5];  const float* db2 = (const float*)d_in[6];
  const float* dw3 = (const float*)d_in[7];  const float* db3 = (const float*)d_in[8];
  const float* cw1 = (const float*)d_in[9];  const float* cb1 = (const float*)d_in[10];
  const float* cw2 = (const float*)d_in[11]; const float* cb2 = (const float*)d_in[12];
  const float* cw3 = (const float*)d_in[13]; const float* cb3 = (const float*)d_in[14];

  char* ws = (char*)d_ws;
  const size_t planes_bytes = 62914560;   // 4*3*256*256*40*2
  ushort* tp  = (ushort*)ws;
  uint4*  wpk = (uint4*)(ws + planes_bytes);

  // opt-in to 128 KB dynamic LDS (idempotent; host-side, capture-safe)
  (void)hipFuncSetAttribute((const void*)fused_k,
                            hipFuncAttributeMaxDynamicSharedMemorySize, 131072);

  prep_k<<<12322, 256, 0, stream>>>(tri, tp, dw1, cw1, dw2, cw2, dw3, cw3, wpk);
  fused_k<<<4096, 512, 131072, stream>>>(tp, coords, vdirs, wpk,
                                         db1, db2, db3, cb1, cb2, cb3,
                                         (float*)d_out);
}